// Round 23
// baseline (81.908 us; speedup 1.0000x reference)
//
#include <hip/hip_runtime.h>
#include <math.h>

#define NTOK 16384
#define DDIM 2048
#define NEXP 64
#define MT   16                  // tokens per block
#define KSPLIT 2
#define KRANGE (DDIM / KSPLIT)   // 1024
#define KCH  128                 // k per chunk
#define NCH  (KRANGE / KCH)      // 8

// ws layout (floats): [0..128] acc (f/P/z), [PART_OFF..] partial logits
// [KSPLIT][NTOK][NEXP] (8.4 MB), [WF_OFF..] W fragments
// bf16[3 levels][4 groups][64 ksteps][64 lanes][8]
#define ACC_N   129
#define PART_OFF 256
#define WF_OFF  (PART_OFF + KSPLIT * NTOK * NEXP)
#define VSTRIDE ((size_t)4 * 64 * 64 * 8)   // ushorts per level

typedef __attribute__((ext_vector_type(8))) short short8_t;
typedef __attribute__((ext_vector_type(4))) float f32x4;

// exact RNE fp32->bf16 (bit trick), and back
__device__ __forceinline__ unsigned short f2bf(float f) {
    unsigned int u = __float_as_uint(f);
    u += 0x7fffu + ((u >> 16) & 1u);
    return (unsigned short)(u >> 16);
}
__device__ __forceinline__ float bf2f(unsigned short s) {
    return __uint_as_float(((unsigned int)s) << 16);
}

// prep: zero acc; split W into 3 exact bf16 levels in MFMA B-fragment order:
// wf[v][g][ks][lane][j] = level_v of W[ks*32+(lane>>4)*8+j][g*16+(lane&15)]
__global__ __launch_bounds__(256) void prep(
    const float* __restrict__ W, float* __restrict__ ws)
{
    const int i = blockIdx.x * 256 + threadIdx.x;   // 0..131071
    if (blockIdx.x == 0 && threadIdx.x < ACC_N) ws[threadIdx.x] = 0.0f;
    const int k = i >> 6, e = i & 63;
    const float v = W[i];
    unsigned short h = f2bf(v);
    float r1 = v - bf2f(h);                 // exact (Sterbenz)
    unsigned short m = f2bf(r1);
    unsigned short l = f2bf(r1 - bf2f(m));  // exact
    unsigned short* wf = (unsigned short*)(ws + WF_OFF);
    const int g = e >> 4, ks = k >> 5;
    const int lane = (((k >> 3) & 3) << 4) | (e & 15);
    const int j = k & 7;
    const size_t base = ((((size_t)g * 64) + ks) * 64 + lane) * 8 + j;
    wf[base] = h;
    wf[VSTRIDE + base] = m;
    wf[2 * VSTRIDE + base] = l;
}

// K-split MFMA gate: grid 2048 = 2 k-splits x 1024 token-tiles ->
// 6 blocks/CU (LDS 24.6 KB, launch_bounds (256,6)) = 24 waves/CU.
// r22 evidence: waves are ~85% latency-stalled; 4 waves/SIMD can't fill the
// issue slots -> raise TLP, keep the proven conv/MFMA core unchanged.
__global__ __launch_bounds__(256, 6) void gate_part(
    const float* __restrict__ x, const unsigned short* __restrict__ wf,
    float* __restrict__ pws)
{
    __shared__ __align__(16) unsigned short xh[2][MT * KCH];   // 2 x 4 KB
    __shared__ __align__(16) unsigned short xm_[2][MT * KCH];  // 2 x 4 KB
    __shared__ __align__(16) unsigned short xl_[2][MT * KCH];  // 2 x 4 KB

    const int tid  = threadIdx.x;
    const int tb   = blockIdx.x & 1023;            // token tile
    const int sp   = blockIdx.x >> 10;             // k-split 0..1
    const int tok0 = tb * MT;
    const int kb   = sp * KRANGE;

    const int lane = tid & 63;
    const int g    = __builtin_amdgcn_readfirstlane(tid >> 6);  // expert group

    // staging: thread owns row = tid>>4, 8 consecutive floats (granule scg)
    const int srow = tid >> 4;
    const int scg  = tid & 15;
    const float* xs = x + (size_t)(tok0 + srow) * DDIM + kb + scg * 8;
    const int wbase = srow * KCH;                   // ushort row base
    const int s0 = (scg ^ (srow & 7)) * 8;          // swizzled granule slot

    // A-fragment addressing: lane holds A[row=lane&15][k=(lane>>4)*8+j]
    const int arow  = lane & 15;
    const int akq   = lane >> 4;
    const int abase = arow * KCH;

    f32x4 acc0 = {0.f, 0.f, 0.f, 0.f};
    f32x4 acc1 = {0.f, 0.f, 0.f, 0.f};
    f32x4 acc2 = {0.f, 0.f, 0.f, 0.f};

    // ---- prologue: conv chunk 0 into buf 0; preload chunk 1 ----
    {
        float4 a0 = *(const float4*)(xs + 0);
        float4 a1 = *(const float4*)(xs + 4);
        float xv[8];
        *(float4*)&xv[0] = a0; *(float4*)&xv[4] = a1;
        unsigned short th[8], tm[8], tl[8];
        #pragma unroll
        for (int i = 0; i < 8; ++i) {
            float f = xv[i];
            th[i] = f2bf(f);
            float r = f - bf2f(th[i]);
            tm[i] = f2bf(r);
            tl[i] = f2bf(r - bf2f(tm[i]));
        }
        *(short8_t*)&xh[0][wbase + s0]  = *(short8_t*)&th[0];
        *(short8_t*)&xm_[0][wbase + s0] = *(short8_t*)&tm[0];
        *(short8_t*)&xl_[0][wbase + s0] = *(short8_t*)&tl[0];
    }
    float4 pv0 = *(const float4*)(xs + KCH + 0);
    float4 pv1 = *(const float4*)(xs + KCH + 4);

    const int ks0 = kb >> 5;          // first global k-step of this split

    #pragma unroll 1
    for (int c = 0; c < NCH; ++c) {
        __syncthreads();   // writes(chunk c) visible; MFMA(c-1) reads done
        const int cb = c & 1, nb = cb ^ 1;

        const unsigned short* wb0 =
            wf + ((((size_t)g * 64) + ks0 + c * 4) * 64 + lane) * 8;
        short8_t B[12];
        #pragma unroll
        for (int s = 0; s < 4; ++s) {
            const unsigned short* wb = wb0 + (size_t)s * 64 * 8;
            B[s * 3 + 0] = *(const short8_t*)&wb[0];
            B[s * 3 + 1] = *(const short8_t*)&wb[VSTRIDE];
            B[s * 3 + 2] = *(const short8_t*)&wb[2 * VSTRIDE];
        }

        if (c + 1 < NCH) {
            // conv + write chunk c+1 (overlaps the B-load latency)
            float xv[8];
            *(float4*)&xv[0] = pv0; *(float4*)&xv[4] = pv1;
            unsigned short th[8], tm[8], tl[8];
            #pragma unroll
            for (int i = 0; i < 8; ++i) {
                float f = xv[i];
                th[i] = f2bf(f);
                float r = f - bf2f(th[i]);      // exact
                tm[i] = f2bf(r);
                tl[i] = f2bf(r - bf2f(tm[i]));  // exact
            }
            *(short8_t*)&xh[nb][wbase + s0]  = *(short8_t*)&th[0];
            *(short8_t*)&xm_[nb][wbase + s0] = *(short8_t*)&tm[0];
            *(short8_t*)&xl_[nb][wbase + s0] = *(short8_t*)&tl[0];
            if (c + 2 < NCH) {
                const float* xn = xs + (c + 2) * KCH;
                pv0 = *(const float4*)(xn + 0);
                pv1 = *(const float4*)(xn + 4);
            }
        }

        // MFMA phase: 4 k-steps x 6 products, 3 independent acc chains
        __builtin_amdgcn_s_setprio(1);
        #pragma unroll
        for (int s = 0; s < 4; ++s) {
            const int slot = (((s * 4 + akq) ^ (arow & 7))) * 8;
            short8_t ah = *(const short8_t*)&xh[cb][abase + slot];
            short8_t am = *(const short8_t*)&xm_[cb][abase + slot];
            short8_t al = *(const short8_t*)&xl_[cb][abase + slot];
            acc0 = __builtin_amdgcn_mfma_f32_16x16x32_bf16(ah, B[s*3+0], acc0, 0, 0, 0);
            acc1 = __builtin_amdgcn_mfma_f32_16x16x32_bf16(ah, B[s*3+1], acc1, 0, 0, 0);
            acc2 = __builtin_amdgcn_mfma_f32_16x16x32_bf16(am, B[s*3+1], acc2, 0, 0, 0);
            acc0 = __builtin_amdgcn_mfma_f32_16x16x32_bf16(ah, B[s*3+2], acc0, 0, 0, 0);
            acc1 = __builtin_amdgcn_mfma_f32_16x16x32_bf16(am, B[s*3+0], acc1, 0, 0, 0);
            acc2 = __builtin_amdgcn_mfma_f32_16x16x32_bf16(al, B[s*3+0], acc2, 0, 0, 0);
        }
        __builtin_amdgcn_s_setprio(0);
    }

    // write partial logits: C layout (m89) col=lane&15, row=(lane>>4)*4+reg
    float* pb = pws + ((size_t)sp * NTOK + tok0) * NEXP;
    #pragma unroll
    for (int r = 0; r < 4; ++r)
        pb[(size_t)(akq * 4 + r) * NEXP + g * 16 + arow] =
            (acc0[r] + acc1[r]) + acc2[r];
}

#define ETOK 64   // tokens per epilogue block

__global__ __launch_bounds__(256) void epilogue(
    const float* __restrict__ pws, const float* __restrict__ bias,
    float* __restrict__ out, float* __restrict__ acc_g)
{
    __shared__ int   f_loc[NEXP];
    __shared__ float p_loc[NEXP];
    __shared__ float z_loc;

    const int tid = threadIdx.x;
    const int tx  = tid & 15;         // expert group: 4tx..4tx+3
    const int tg  = tid >> 4;         // token slot 0..15
    const int e0  = tx * 4;

    if (tid < NEXP) { f_loc[tid] = 0; p_loc[tid] = 0.0f; }
    if (tid == 0) z_loc = 0.0f;
    __syncthreads();

    float bb[4];
    *(float4*)bb = *(const float4*)&bias[e0];

    float pacc[4] = {0.f, 0.f, 0.f, 0.f};
    float zacc = 0.0f;

    for (int it = 0; it < ETOK / 16; ++it) {
        const int gt = blockIdx.x * ETOK + it * 16 + tg;

        // sum 2 partials in fixed ascending order, then + bias
        float l[4];
        {
            const size_t ro = (size_t)gt * NEXP + e0;
            float4 q0 = *(const float4*)&pws[ro];
            float4 q1 = *(const float4*)&pws[(size_t)NTOK * NEXP + ro];
            l[0] = (q0.x + q1.x) + bb[0];
            l[1] = (q0.y + q1.y) + bb[1];
            l[2] = (q0.z + q1.z) + bb[2];
            l[3] = (q0.w + q1.w) + bb[3];
        }

        // local top-2 (stable: ascending e, strict >)
        float v1 = l[0], v2 = -INFINITY;
        int   i1 = e0,   i2 = 0x7fffffff;
        #pragma unroll
        for (int j = 1; j < 4; ++j) {
            float v = l[j]; int e = e0 + j;
            if (v > v1)      { v2 = v1; i2 = i1; v1 = v; i1 = e; }
            else if (v > v2) { v2 = v;  i2 = e; }
        }
        // merge across the 16 lanes of this token (value desc, idx asc)
        #pragma unroll
        for (int off = 1; off < 16; off <<= 1) {
            float o1 = __shfl_xor(v1, off, 16); int oi1 = __shfl_xor(i1, off, 16);
            float o2 = __shfl_xor(v2, off, 16); int oi2 = __shfl_xor(i2, off, 16);
            if (o1 > v1 || (o1 == v1 && oi1 < i1)) {
                float cs = v1; int ci = i1;
                v1 = o1; i1 = oi1;
                if (cs > o2 || (cs == o2 && ci < oi2)) { v2 = cs; i2 = ci;  }
                else                                   { v2 = o2; i2 = oi2; }
            } else {
                if (o1 > v2 || (o1 == v2 && oi1 < i2)) { v2 = o1; i2 = oi1; }
            }
        }
        const float mx = v1;

        float sden[4], dsum = 0.0f;
        #pragma unroll
        for (int j = 0; j < 4; ++j) { sden[j] = __expf(l[j] - mx); dsum += sden[j]; }
        #pragma unroll
        for (int off = 1; off < 16; off <<= 1) dsum += __shfl_xor(dsum, off, 16);
        const float inv = 1.0f / dsum;

        float zsum = 0.0f;
        #pragma unroll
        for (int j = 0; j < 4; ++j) {
            float pj = sden[j] * inv;
            pacc[j] += pj;
            zsum += __expf(pj);
        }
        #pragma unroll
        for (int off = 1; off < 16; off <<= 1) zsum += __shfl_xor(zsum, off, 16);

        if (tx == 0) {
            const float s2 = __expf(v2 - mx);      // s1 == 1
            const float ci = 1.0f / (1.0f + s2);
            out[2 * gt]     = (float)i1;
            out[2 * gt + 1] = (float)i2;
            out[2 * NTOK + 2 * gt]     = ci;
            out[2 * NTOK + 2 * gt + 1] = s2 * ci;
            atomicAdd(&f_loc[i1], 1);
            float lse = __logf(zsum);
            zacc += lse * lse;
        }
    }

    // z: wave-reduce (only tx==0 lanes carry nonzero), one LDS atomic per wave
    #pragma unroll
    for (int off = 1; off < 64; off <<= 1) zacc += __shfl_xor(zacc, off);
    if ((tid & 63) == 0) atomicAdd(&z_loc, zacc);

    // P: fold token-groups within wave, then LDS
    #pragma unroll
    for (int j = 0; j < 4; ++j) {
        pacc[j] += __shfl_xor(pacc[j], 16);
        pacc[j] += __shfl_xor(pacc[j], 32);
    }
    if ((tid & 63) < 16) {
        #pragma unroll
        for (int j = 0; j < 4; ++j) atomicAdd(&p_loc[e0 + j], pacc[j]);
    }

    __syncthreads();
    if (tid < NEXP) {
        atomicAdd(&acc_g[64 + tid], p_loc[tid]);
        if (f_loc[tid]) atomicAdd(&acc_g[tid], (float)f_loc[tid]);
    }
    if (tid == 0) atomicAdd(&acc_g[128], z_loc);
}

__global__ void gate_finalize(const float* __restrict__ acc, float* __restrict__ out) {
    int e = threadIdx.x;  // 64 threads
    float v = acc[e] * acc[64 + e];
    #pragma unroll
    for (int off = 32; off > 0; off >>= 1) v += __shfl_down(v, off);
    if (e == 0) {
        const float NT = (float)NTOK;
        out[2 * NTOK * 2]     = 0.01f * (v / (float)NEXP) / (NT * NT);
        out[2 * NTOK * 2 + 1] = 0.1f * acc[128] / NT;
    }
}

extern "C" void kernel_launch(void* const* d_in, const int* in_sizes, int n_in,
                              void* d_out, int out_size, void* d_ws, size_t ws_size,
                              hipStream_t stream) {
    const float* x    = (const float*)d_in[0];
    const float* W    = (const float*)d_in[1];
    const float* bias = (const float*)d_in[2];
    float* out = (float*)d_out;
    float* ws  = (float*)d_ws;
    float* pws = ws + PART_OFF;
    const unsigned short* wfrag = (const unsigned short*)(ws + WF_OFF);

    prep<<<(DDIM * NEXP) / 256, 256, 0, stream>>>(W, ws);
    gate_part<<<KSPLIT * (NTOK / MT), 256, 0, stream>>>(x, wfrag, pws);
    epilogue<<<NTOK / ETOK, 256, 0, stream>>>(pws, bias, out, ws);
    gate_finalize<<<1, 64, 0, stream>>>(ws, out);
}

// Round 24
// 65.842 us; speedup vs baseline: 1.2440x; 1.2440x over previous
//
#include <hip/hip_runtime.h>
#include <math.h>

#define NTOK 16384
#define DDIM 2048
#define NEXP 64
#define MT   32                  // tokens per block (2 quads of 16)
#define KCH  64                  // k per chunk
#define NCH  (DDIM / KCH)        // 32

// ws layout: [0..128] acc (f counts / P sums / z). floats.
// [WF_OFF ...] W fragments: bf16[3 levels][4 groups][64 ksteps][64 lanes][8]
#define ACC_N  129
#define WF_OFF 256
#define VSTRIDE ((size_t)4 * 64 * 64 * 8)   // ushorts per level

typedef __attribute__((ext_vector_type(8))) short short8_t;
typedef __attribute__((ext_vector_type(4))) float f32x4;

// exact RNE fp32->bf16 (bit trick), and back
__device__ __forceinline__ unsigned short f2bf(float f) {
    unsigned int u = __float_as_uint(f);
    u += 0x7fffu + ((u >> 16) & 1u);
    return (unsigned short)(u >> 16);
}
__device__ __forceinline__ float bf2f(unsigned short s) {
    return __uint_as_float(((unsigned int)s) << 16);
}

// prep: zero acc; split W into 3 exact bf16 levels in MFMA B-fragment order:
// wf[v][g][ks][lane][j] = level_v of W[ks*32+(lane>>4)*8+j][g*16+(lane&15)]
__global__ __launch_bounds__(256) void prep(
    const float* __restrict__ W, float* __restrict__ ws)
{
    const int i = blockIdx.x * 256 + threadIdx.x;   // 0..131071
    if (blockIdx.x == 0 && threadIdx.x < ACC_N) ws[threadIdx.x] = 0.0f;
    const int k = i >> 6, e = i & 63;
    const float v = W[i];
    unsigned short h = f2bf(v);
    float r1 = v - bf2f(h);                 // exact (Sterbenz)
    unsigned short m = f2bf(r1);
    unsigned short l = f2bf(r1 - bf2f(m));  // exact
    unsigned short* wf = (unsigned short*)(ws + WF_OFF);
    const int g = e >> 4, ks = k >> 5;
    const int lane = (((k >> 3) & 3) << 4) | (e & 15);
    const int j = k & 7;
    const size_t base = ((((size_t)g * 64) + ks) * 64 + lane) * 8 + j;
    wf[base] = h;
    wf[VSTRIDE + base] = m;
    wf[2 * VSTRIDE + base] = l;
}

// split-convert 8 fp32 -> 3 bf16 levels, store to swizzled LDS slots
__device__ __forceinline__ void conv_store(
    unsigned short* dh, unsigned short* dm, unsigned short* dl,
    float4 a0, float4 a1)
{
    float xv[8];
    *(float4*)&xv[0] = a0; *(float4*)&xv[4] = a1;
    unsigned short th[8], tm[8], tl[8];
    #pragma unroll
    for (int i = 0; i < 8; ++i) {
        float f = xv[i];
        th[i] = f2bf(f);
        float r = f - bf2f(th[i]);      // exact
        tm[i] = f2bf(r);
        tl[i] = f2bf(r - bf2f(tm[i]));  // exact
    }
    *(short8_t*)dh = *(short8_t*)&th[0];
    *(short8_t*)dm = *(short8_t*)&tm[0];
    *(short8_t*)dl = *(short8_t*)&tl[0];
}

// Fused MFMA gate, MT=32: each wave owns 2 token-quads x 16 experts.
// Per k-step ONE set of B loads feeds 12 MFMAs (B reuse x2) -> B-fragment
// L2 traffic halves (786->393 MB, the largest reducible term at the r18-r23
// latency plateau) and per-wave issue duty doubles. Core conv/MFMA sequence,
// swizzle, and numerics are bit-identical per token to r22/r23.
__global__ __launch_bounds__(256, 4) void gate_fused(
    const float* __restrict__ x, const unsigned short* __restrict__ wf,
    const float* __restrict__ bias, float* __restrict__ out,
    float* __restrict__ acc_g)
{
    __shared__ __align__(16) unsigned short xh[2][MT * KCH];   // 2 x 4 KB
    __shared__ __align__(16) unsigned short xm_[2][MT * KCH];  // 2 x 4 KB
    __shared__ __align__(16) unsigned short xl_[2][MT * KCH];  // 2 x 4 KB
    __shared__ float logits[MT][68];
    __shared__ int   f_loc[NEXP];
    __shared__ float p_loc[NEXP];
    __shared__ float z_loc;

    const int tid  = threadIdx.x;
    const int tok0 = blockIdx.x * MT;
    const int lane = tid & 63;
    const int g    = __builtin_amdgcn_readfirstlane(tid >> 6);  // expert group

    if (tid < NEXP) { f_loc[tid] = 0; p_loc[tid] = 0.0f; }
    if (tid == 0) z_loc = 0.0f;

    // staging: thread owns row = tid>>3 (0..31), granule scg = tid&7
    const int srow = tid >> 3;
    const int scg  = tid & 7;
    const float* xs = x + (size_t)(tok0 + srow) * DDIM + scg * 8;
    const int wbase = srow * KCH;                  // ushort row base
    const int s0 = ((scg ^ (srow & 7))) * 8;       // swizzled granule slot

    // A-fragment addressing: lane l, quad q -> row 16q+(l&15),
    // k = kstep*32 + (l>>4)*8 + j. (row&7) == (l&15)&7: q-invariant.
    const int arow16 = lane & 15;
    const int akq    = lane >> 4;
    const int asw    = arow16 & 7;

    f32x4 acc[2][3];
    #pragma unroll
    for (int q = 0; q < 2; ++q)
        #pragma unroll
        for (int ch = 0; ch < 3; ++ch)
            acc[q][ch] = (f32x4){0.f, 0.f, 0.f, 0.f};

    // ---- prologue: conv chunk 0 into buf 0; preload chunk 1 ----
    {
        float4 a0 = *(const float4*)(xs + 0);
        float4 a1 = *(const float4*)(xs + 4);
        conv_store(&xh[0][wbase + s0], &xm_[0][wbase + s0],
                   &xl_[0][wbase + s0], a0, a1);
    }
    float4 pv0 = *(const float4*)(xs + KCH + 0);
    float4 pv1 = *(const float4*)(xs + KCH + 4);

    #pragma unroll 1
    for (int c = 0; c < NCH; ++c) {
        __syncthreads();   // writes(chunk c) visible; MFMA(c-1) reads done
        const int cb = c & 1, nb = cb ^ 1;

        if (c + 1 < NCH) {
            // conv + write chunk c+1 (overlaps MFMA below)
            conv_store(&xh[nb][wbase + s0], &xm_[nb][wbase + s0],
                       &xl_[nb][wbase + s0], pv0, pv1);
            if (c + 2 < NCH) {
                const float* xn = xs + (c + 2) * KCH;
                pv0 = *(const float4*)(xn + 0);
                pv1 = *(const float4*)(xn + 4);
            }
        }

        // MFMA phase: 2 k-steps x (1 B-set x 2 quads x 6 products)
        __builtin_amdgcn_s_setprio(1);
        #pragma unroll
        for (int s = 0; s < 2; ++s) {
            const int ks = c * 2 + s;
            const unsigned short* wb =
                wf + ((((size_t)g * 64) + ks) * 64 + lane) * 8;
            short8_t bh = *(const short8_t*)&wb[0];
            short8_t bm = *(const short8_t*)&wb[VSTRIDE];
            short8_t bl = *(const short8_t*)&wb[2 * VSTRIDE];
            const int slot = (((s * 4 + akq) ^ asw)) * 8;
            #pragma unroll
            for (int q = 0; q < 2; ++q) {
                const int ab = (16 * q + arow16) * KCH + slot;
                short8_t ah = *(const short8_t*)&xh[cb][ab];
                short8_t am = *(const short8_t*)&xm_[cb][ab];
                short8_t al = *(const short8_t*)&xl_[cb][ab];
                acc[q][0] = __builtin_amdgcn_mfma_f32_16x16x32_bf16(ah, bh, acc[q][0], 0, 0, 0);
                acc[q][1] = __builtin_amdgcn_mfma_f32_16x16x32_bf16(ah, bm, acc[q][1], 0, 0, 0);
                acc[q][2] = __builtin_amdgcn_mfma_f32_16x16x32_bf16(am, bm, acc[q][2], 0, 0, 0);
                acc[q][0] = __builtin_amdgcn_mfma_f32_16x16x32_bf16(ah, bl, acc[q][0], 0, 0, 0);
                acc[q][1] = __builtin_amdgcn_mfma_f32_16x16x32_bf16(am, bh, acc[q][1], 0, 0, 0);
                acc[q][2] = __builtin_amdgcn_mfma_f32_16x16x32_bf16(al, bh, acc[q][2], 0, 0, 0);
            }
        }
        __builtin_amdgcn_s_setprio(0);
    }

    // C layout (m89): col = lane&15, row(within quad) = (lane>>4)*4 + reg
    #pragma unroll
    for (int q = 0; q < 2; ++q)
        #pragma unroll
        for (int r = 0; r < 4; ++r)
            logits[16 * q + akq * 4 + r][g * 16 + arow16] =
                (acc[q][0][r] + acc[q][1][r]) + acc[q][2][r];
    __syncthreads();

    // ---- fused epilogue (r23-verified logic), 2 x 16-token groups ----
    const int tx  = tid & 15;         // expert group of 4
    const int tgs = tid >> 4;         // token slot 0..15
    const int e0  = tx * 4;

    float bb[4];
    *(float4*)bb = *(const float4*)&bias[e0];

    float pacc[4] = {0.f, 0.f, 0.f, 0.f};
    float zacc = 0.0f;

    #pragma unroll
    for (int it = 0; it < 2; ++it) {
        const int t  = it * 16 + tgs;
        const int gt = tok0 + t;

        float l[4];
        {
            float4 lv = *(const float4*)&logits[t][e0];
            l[0] = lv.x + bb[0]; l[1] = lv.y + bb[1];
            l[2] = lv.z + bb[2]; l[3] = lv.w + bb[3];
        }

        // local top-2 (stable: ascending e, strict >)
        float v1 = l[0], v2 = -INFINITY;
        int   i1 = e0,   i2 = 0x7fffffff;
        #pragma unroll
        for (int j = 1; j < 4; ++j) {
            float v = l[j]; int e = e0 + j;
            if (v > v1)      { v2 = v1; i2 = i1; v1 = v; i1 = e; }
            else if (v > v2) { v2 = v;  i2 = e; }
        }
        // merge across the 16 lanes of this token (value desc, idx asc)
        #pragma unroll
        for (int off = 1; off < 16; off <<= 1) {
            float o1 = __shfl_xor(v1, off, 16); int oi1 = __shfl_xor(i1, off, 16);
            float o2 = __shfl_xor(v2, off, 16); int oi2 = __shfl_xor(i2, off, 16);
            if (o1 > v1 || (o1 == v1 && oi1 < i1)) {
                float cs = v1; int ci = i1;
                v1 = o1; i1 = oi1;
                if (cs > o2 || (cs == o2 && ci < oi2)) { v2 = cs; i2 = ci;  }
                else                                   { v2 = o2; i2 = oi2; }
            } else {
                if (o1 > v2 || (o1 == v2 && oi1 < i2)) { v2 = o1; i2 = oi1; }
            }
        }
        const float mx = v1;

        float sden[4], dsum = 0.0f;
        #pragma unroll
        for (int j = 0; j < 4; ++j) { sden[j] = __expf(l[j] - mx); dsum += sden[j]; }
        #pragma unroll
        for (int off = 1; off < 16; off <<= 1) dsum += __shfl_xor(dsum, off, 16);
        const float inv = 1.0f / dsum;

        float zsum = 0.0f;
        #pragma unroll
        for (int j = 0; j < 4; ++j) {
            float pj = sden[j] * inv;
            pacc[j] += pj;
            zsum += __expf(pj);
        }
        #pragma unroll
        for (int off = 1; off < 16; off <<= 1) zsum += __shfl_xor(zsum, off, 16);

        if (tx == 0) {
            const float s2 = __expf(v2 - mx);      // s1 == 1
            const float ci = 1.0f / (1.0f + s2);
            out[2 * gt]     = (float)i1;
            out[2 * gt + 1] = (float)i2;
            out[2 * NTOK + 2 * gt]     = ci;
            out[2 * NTOK + 2 * gt + 1] = s2 * ci;
            atomicAdd(&f_loc[i1], 1);
            float lse = __logf(zsum);
            zacc += lse * lse;
        }
    }

    // z: wave-reduce (only tx==0 lanes nonzero), one LDS atomic per wave
    #pragma unroll
    for (int off = 1; off < 64; off <<= 1) zacc += __shfl_xor(zacc, off);
    if ((tid & 63) == 0) atomicAdd(&z_loc, zacc);

    // P: fold token-groups within wave, then LDS
    #pragma unroll
    for (int j = 0; j < 4; ++j) {
        pacc[j] += __shfl_xor(pacc[j], 16);
        pacc[j] += __shfl_xor(pacc[j], 32);
    }
    if ((tid & 63) < 16) {
        #pragma unroll
        for (int j = 0; j < 4; ++j) atomicAdd(&p_loc[e0 + j], pacc[j]);
    }

    __syncthreads();
    if (tid < NEXP) {
        atomicAdd(&acc_g[64 + tid], p_loc[tid]);
        if (f_loc[tid]) atomicAdd(&acc_g[tid], (float)f_loc[tid]);
    }
    if (tid == 0) atomicAdd(&acc_g[128], z_loc);
}

__global__ void gate_finalize(const float* __restrict__ acc, float* __restrict__ out) {
    int e = threadIdx.x;  // 64 threads
    float v = acc[e] * acc[64 + e];
    #pragma unroll
    for (int off = 32; off > 0; off >>= 1) v += __shfl_down(v, off);
    if (e == 0) {
        const float NT = (float)NTOK;
        out[2 * NTOK * 2]     = 0.01f * (v / (float)NEXP) / (NT * NT);
        out[2 * NTOK * 2 + 1] = 0.1f * acc[128] / NT;
    }
}

extern "C" void kernel_launch(void* const* d_in, const int* in_sizes, int n_in,
                              void* d_out, int out_size, void* d_ws, size_t ws_size,
                              hipStream_t stream) {
    const float* x    = (const float*)d_in[0];
    const float* W    = (const float*)d_in[1];
    const float* bias = (const float*)d_in[2];
    float* out = (float*)d_out;
    float* ws  = (float*)d_ws;
    const unsigned short* wfrag = (const unsigned short*)(ws + WF_OFF);

    prep<<<(DDIM * NEXP) / 256, 256, 0, stream>>>(W, ws);
    gate_fused<<<NTOK / MT, 256, 0, stream>>>(x, wfrag, bias, out, ws);
    gate_finalize<<<1, 64, 0, stream>>>(ws, out);
}